// Round 1
// baseline (250.232 us; speedup 1.0000x reference)
//
#include <hip/hip_runtime.h>
#include <math.h>

// EdgeGAT: B=8, OP=400, MA=200, F=64. f32 in/out, adj int32.
// v2: single-pass fused kernel. One block per (b,m); per-wave active-row
// compaction (ballot prefix) -> dense branch-free online-softmax stream over z
// (read ONCE, lane=feature, 6x shfl_xor dot) -> cross-wave merge -> fused
// 3-GEMV epilogue. Eliminates second z pass, partials buffer, and 3rd kernel.
#define B_   8
#define OP_  400
#define MA_  200
#define ZROW (MA_ * 64)
#define NEGM -1.0e30f

// ---------------- kernel 1: precompute (wave-per-row) ----------------
// w_e = W_edge@a_edge ; e_op[b,n] = x[b,n,:].(W_op@a_op) ; e_ma[b,m] = y[b,m,:].(W_ma@a_ma)
__global__ __launch_bounds__(256) void precompute_k(
    const float* __restrict__ x, const float* __restrict__ y,
    const float* __restrict__ Wop, const float* __restrict__ Wma,
    const float* __restrict__ Wedge, const float* __restrict__ att,
    float* __restrict__ ws_we, float* __restrict__ ws_eop, float* __restrict__ ws_ema)
{
    __shared__ float w_s[192];
    const int tid = threadIdx.x, wv = tid >> 6, ln = tid & 63;
    if (tid < 192) {
        const int which = tid >> 6, i = tid & 63;
        const float* W = (which == 0) ? Wop : ((which == 1) ? Wma : Wedge);
        const float* a = att + which * 64;
        float acc = 0.f;
        #pragma unroll 8
        for (int f = 0; f < 64; ++f) acc = fmaf(W[i * 64 + f], a[f], acc);
        w_s[tid] = acc;
    }
    __syncthreads();
    if (blockIdx.x == 0 && tid < 64) ws_we[tid] = w_s[128 + tid];

    const int row = blockIdx.x * 4 + wv;           // 0 .. 4799
    if (row < B_ * OP_) {
        float s = x[(size_t)row * 64 + ln] * w_s[ln];
        #pragma unroll
        for (int o = 32; o > 0; o >>= 1) s += __shfl_xor(s, o, 64);
        if (ln == 0) ws_eop[row] = s;
    } else if (row < B_ * OP_ + B_ * MA_) {
        const int r2 = row - B_ * OP_;
        float s = y[(size_t)r2 * 64 + ln] * w_s[64 + ln];
        #pragma unroll
        for (int o = 32; o > 0; o >>= 1) s += __shfl_xor(s, o, 64);
        if (ln == 0) ws_ema[r2] = s;
    }
}

// ---------------- kernel 2: fused stream + softmax + epilogue ----------------
// block = (b,m). 4 waves x 100 rows. z read exactly once.
__global__ __launch_bounds__(256) void gat_fused(
    const float* __restrict__ x, const float* __restrict__ y,
    const float* __restrict__ z, const int* __restrict__ adj,
    const float* __restrict__ Wop, const float* __restrict__ Wma,
    const float* __restrict__ Wedge,
    const float* __restrict__ ws_we, const float* __restrict__ ws_eop,
    const float* __restrict__ ws_ema, float* __restrict__ out)
{
    __shared__ int   ln_s[4][104];     // compacted active n per wave
    __shared__ float le_s[4][104];     // staged e_op[n] + e_ma  (NEGM for pad)
    __shared__ float mred[4], lred[4];
    __shared__ float vws[4][64], uws[4][64];
    __shared__ float vs_s[64], us_s[64], ys_s[64];
    __shared__ float pvt[4][64];

    const int tid = threadIdx.x, wv = tid >> 6, ln = tid & 63;
    const int bm = blockIdx.x;
    const int b = bm / MA_, m = bm % MA_;

    const float ema = ws_ema[bm];
    const float wl  = ws_we[ln];                 // w_e, lane=feature

    // ---- per-wave active-row compaction (rows rbase..rbase+99) ----
    const int rbase = wv * 100;
    int cnt = 0;
    #pragma unroll
    for (int round = 0; round < 2; ++round) {
        const int lr = round * 64 + ln;          // 0..127
        const int n  = rbase + lr;
        bool a = false;
        if (lr < 100) a = (adj[((size_t)(b * OP_ + n)) * MA_ + m] != 0);
        const unsigned long long mask = __ballot(a);
        if (a) {
            const int pos = cnt + __popcll(mask & ((1ull << ln) - 1ull));
            ln_s[wv][pos] = n;
            le_s[wv][pos] = ws_eop[b * OP_ + n] + ema;
        }
        cnt += __popcll(mask);
    }
    // pad to multiple of 4 with p==0 sentinels (valid address, e -> -inf)
    const int cnt_p = (cnt + 3) & ~3;
    if (ln < cnt_p - cnt) {
        ln_s[wv][cnt + ln] = rbase;
        le_s[wv][cnt + ln] = NEGM;
    }
    // list is per-wave (no cross-wave reads): no barrier needed here.

    const float* zb = z + ((size_t)b * OP_ * MA_ + m) * 64;
    const float* xb = x + (size_t)b * OP_ * 64;

    float M = NEGM, L = 0.f, v = 0.f, u = 0.f;

    #define UPD(zv, xv, eo) do {                                   \
        float s_ = (zv) * wl;                                      \
        s_ += __shfl_xor(s_, 1, 64);  s_ += __shfl_xor(s_, 2, 64); \
        s_ += __shfl_xor(s_, 4, 64);  s_ += __shfl_xor(s_, 8, 64); \
        s_ += __shfl_xor(s_, 16, 64); s_ += __shfl_xor(s_, 32, 64);\
        float e_ = s_ + (eo);                                      \
        e_ = (e_ >= 0.f) ? e_ : 0.01f * e_;                        \
        const float m2_ = fmaxf(M, e_);                            \
        const float c_  = __expf(M - m2_);                         \
        const float p_  = __expf(e_ - m2_);                        \
        L = fmaf(L, c_, p_);                                       \
        v = fmaf(v, c_, p_ * (zv));                                \
        u = fmaf(u, c_, p_ * (xv));                                \
        M = m2_;                                                   \
    } while (0)

    // ---- single streaming pass: groups of 4 rows, 8 loads in flight ----
    for (int i = 0; i < cnt_p; i += 4) {
        const int n0 = __builtin_amdgcn_readfirstlane(ln_s[wv][i + 0]);
        const int n1 = __builtin_amdgcn_readfirstlane(ln_s[wv][i + 1]);
        const int n2 = __builtin_amdgcn_readfirstlane(ln_s[wv][i + 2]);
        const int n3 = __builtin_amdgcn_readfirstlane(ln_s[wv][i + 3]);
        const float z0 = zb[(size_t)n0 * ZROW + ln];
        const float z1 = zb[(size_t)n1 * ZROW + ln];
        const float z2 = zb[(size_t)n2 * ZROW + ln];
        const float z3 = zb[(size_t)n3 * ZROW + ln];
        const float x0 = xb[(size_t)n0 * 64 + ln];
        const float x1 = xb[(size_t)n1 * 64 + ln];
        const float x2 = xb[(size_t)n2 * 64 + ln];
        const float x3 = xb[(size_t)n3 * 64 + ln];
        const float e0 = le_s[wv][i + 0];
        const float e1 = le_s[wv][i + 1];
        const float e2 = le_s[wv][i + 2];
        const float e3 = le_s[wv][i + 3];
        UPD(z0, x0, e0);
        UPD(z1, x1, e1);
        UPD(z2, x2, e2);
        UPD(z3, x3, e3);
    }
    #undef UPD

    // ---- cross-wave online-softmax merge ----
    if (ln == 0) { mred[wv] = M; lred[wv] = L; }   // M,L wave-uniform
    vws[wv][ln] = v;
    uws[wv][ln] = u;
    __syncthreads();

    if (tid < 64) {
        const float Mg = fmaxf(fmaxf(mred[0], mred[1]), fmaxf(mred[2], mred[3]));
        const float c0 = __expf(mred[0] - Mg);
        const float c1 = __expf(mred[1] - Mg);
        const float c2 = __expf(mred[2] - Mg);
        const float c3 = __expf(mred[3] - Mg);
        const float Lg = c0 * lred[0] + c1 * lred[1] + c2 * lred[2] + c3 * lred[3];
        const float inv = (Lg > 0.f) ? (1.f / Lg) : 0.f;   // row_empty -> 0
        vs_s[tid] = (c0 * vws[0][tid] + c1 * vws[1][tid] +
                     c2 * vws[2][tid] + c3 * vws[3][tid]) * inv;
        us_s[tid] = (c0 * uws[0][tid] + c1 * uws[1][tid] +
                     c2 * uws[2][tid] + c3 * uws[3][tid]) * inv;
        ys_s[tid] = y[(size_t)bm * 64 + tid];
    }
    __syncthreads();

    // ---- fused epilogue: h = v@We + u@Wop + y@Wma ; waves split i ----
    {
        float acc = 0.f;
        const int i0 = wv * 16;
        #pragma unroll
        for (int k = 0; k < 16; ++k) {
            const int i = i0 + k;
            acc += vs_s[i] * Wedge[i * 64 + ln]
                 + us_s[i] * Wop[i * 64 + ln]
                 + ys_s[i] * Wma[i * 64 + ln];
        }
        pvt[wv][ln] = acc;
    }
    __syncthreads();
    if (tid < 64) {
        const float h = pvt[0][tid] + pvt[1][tid] + pvt[2][tid] + pvt[3][tid];
        out[(size_t)bm * 64 + tid] = (h > 0.f) ? h : (__expf(h) - 1.f);
    }
}

extern "C" void kernel_launch(void* const* d_in, const int* in_sizes, int n_in,
                              void* d_out, int out_size, void* d_ws, size_t ws_size,
                              hipStream_t stream) {
    const float* x     = (const float*)d_in[0];
    const float* y     = (const float*)d_in[1];
    const float* z     = (const float*)d_in[2];
    const int*   adj   = (const int*)d_in[3];
    const float* Wop   = (const float*)d_in[4];
    const float* Wma   = (const float*)d_in[5];
    const float* Wedge = (const float*)d_in[6];
    const float* att   = (const float*)d_in[7];

    float* ws     = (float*)d_ws;
    float* ws_we  = ws;                              // 64
    float* ws_eop = ws + 64;                         // B*OP = 3200
    float* ws_ema = ws + 64 + B_ * OP_;              // B*MA = 1600

    precompute_k<<<1200, 256, 0, stream>>>(
        x, y, Wop, Wma, Wedge, att, ws_we, ws_eop, ws_ema);
    gat_fused<<<B_ * MA_, 256, 0, stream>>>(
        x, y, z, adj, Wop, Wma, Wedge, ws_we, ws_eop, ws_ema, (float*)d_out);
}

// Round 5
// 240.086 us; speedup vs baseline: 1.0423x; 1.0423x over previous
//
#include <hip/hip_runtime.h>
#include <math.h>

// EdgeGAT: B=8, OP=400, MA=200, F=64. f32 in/out, adj int32.
// v3.1: single-pass fused kernel, quad-of-16 streaming layout.
// (v3 failed to compile: __builtin_nontemporal_load rejects HIP float4;
//  switched streamed vectors to clang ext_vector_type(4) float.)
// Block = (b,m), 4 waves x 100 rows. Per-wave active-row compaction
// (ballot prefix) -> dense stream over z in groups of 8 rows:
//   lane = (group g=ln>>4 owns a row, quad q=ln&15 owns 4 features)
//   1 dwordx4 load = 4 z-rows; dot = 4 intra-16 shfl_xor shared by 4 rows;
//   per-group online softmax (M,L) + per-lane v4f (v,u) accumulators.
// Group merge (xor 16/32 folds) -> cross-wave merge -> fused 3-GEMV epilogue.
#define B_   8
#define OP_  400
#define MA_  200
#define ZROW (MA_ * 64)
#define NEGM -1.0e30f

typedef float v4f __attribute__((ext_vector_type(4)));

// ---------------- kernel 1: precompute (wave-per-row) ----------------
// w_e = W_edge@a_edge ; e_op[b,n] = x[b,n,:].(W_op@a_op) ; e_ma[b,m] = y[b,m,:].(W_ma@a_ma)
__global__ __launch_bounds__(256) void precompute_k(
    const float* __restrict__ x, const float* __restrict__ y,
    const float* __restrict__ Wop, const float* __restrict__ Wma,
    const float* __restrict__ Wedge, const float* __restrict__ att,
    float* __restrict__ ws_we, float* __restrict__ ws_eop, float* __restrict__ ws_ema)
{
    __shared__ float w_s[192];
    const int tid = threadIdx.x, wv = tid >> 6, ln = tid & 63;
    if (tid < 192) {
        const int which = tid >> 6, i = tid & 63;
        const float* W = (which == 0) ? Wop : ((which == 1) ? Wma : Wedge);
        const float* a = att + which * 64;
        float acc = 0.f;
        #pragma unroll 8
        for (int f = 0; f < 64; ++f) acc = fmaf(W[i * 64 + f], a[f], acc);
        w_s[tid] = acc;
    }
    __syncthreads();
    if (blockIdx.x == 0 && tid < 64) ws_we[tid] = w_s[128 + tid];

    const int row = blockIdx.x * 4 + wv;           // 0 .. 4799
    if (row < B_ * OP_) {
        float s = x[(size_t)row * 64 + ln] * w_s[ln];
        #pragma unroll
        for (int o = 32; o > 0; o >>= 1) s += __shfl_xor(s, o, 64);
        if (ln == 0) ws_eop[row] = s;
    } else if (row < B_ * OP_ + B_ * MA_) {
        const int r2 = row - B_ * OP_;
        float s = y[(size_t)r2 * 64 + ln] * w_s[64 + ln];
        #pragma unroll
        for (int o = 32; o > 0; o >>= 1) s += __shfl_xor(s, o, 64);
        if (ln == 0) ws_ema[r2] = s;
    }
}

// ---------------- kernel 2: fused stream + softmax + epilogue ----------------
__global__ __launch_bounds__(256) void gat_fused(
    const float* __restrict__ x, const float* __restrict__ y,
    const float* __restrict__ z, const int* __restrict__ adj,
    const float* __restrict__ Wop, const float* __restrict__ Wma,
    const float* __restrict__ Wedge,
    const float* __restrict__ ws_we, const float* __restrict__ ws_eop,
    const float* __restrict__ ws_ema, float* __restrict__ out)
{
    __shared__ int   ln_s[4][112];     // compacted active n per wave (pad to 8)
    __shared__ float le_s[4][112];     // staged e_op[n] + e_ma  (NEGM for pad)
    __shared__ float mred[4], lred[4];
    __shared__ float vws[4][64], uws[4][64];
    __shared__ float vs_s[64], us_s[64], ys_s[64];
    __shared__ float pvt[4][64];

    const int tid = threadIdx.x, wv = tid >> 6, ln = tid & 63;
    const int g = ln >> 4, q = ln & 15;            // group / feature-quad
    const int bm = blockIdx.x;
    const int b = bm / MA_, m = bm % MA_;

    const float ema = ws_ema[bm];

    // ---- per-wave active-row compaction (rows rbase..rbase+99) ----
    const int rbase = wv * 100;
    int cnt = 0;
    #pragma unroll
    for (int round = 0; round < 2; ++round) {
        const int lr = round * 64 + ln;            // 0..127
        const int n  = rbase + lr;
        bool a = false;
        if (lr < 100) a = (adj[((size_t)(b * OP_ + n)) * MA_ + m] != 0);
        const unsigned long long mask = __ballot(a);
        if (a) {
            const int pos = cnt + __popcll(mask & ((1ull << ln) - 1ull));
            ln_s[wv][pos] = n;
            le_s[wv][pos] = ws_eop[b * OP_ + n] + ema;
        }
        cnt += __popcll(mask);
    }
    // pad to multiple of 8 with sentinels (valid address, e -> -inf)
    const int cnt_p = (cnt + 7) & ~7;
    if (ln < cnt_p - cnt) {
        ln_s[wv][cnt + ln] = rbase;
        le_s[wv][cnt + ln] = NEGM;
    }
    // list is per-wave (no cross-wave reads): no barrier needed here.

    const float* zP = z + ((size_t)b * OP_ * MA_ + m) * 64;
    const float* xP = x + (size_t)b * OP_ * 64;
    const v4f wq = ((const v4f*)ws_we)[q];         // w_e quad for this lane

    v4f v = {0.f, 0.f, 0.f, 0.f}, u = {0.f, 0.f, 0.f, 0.f};
    float M = NEGM, L = 0.f;

    // Per-group online-softmax update: 4 intra-16 shuffles shared by the quad.
    #define UPD(z4, x4, eo) do {                                               \
        float s_ = fmaf((z4).x, wq.x, fmaf((z4).y, wq.y,                       \
                   fmaf((z4).z, wq.z, (z4).w * wq.w)));                        \
        s_ += __shfl_xor(s_, 1, 64); s_ += __shfl_xor(s_, 2, 64);              \
        s_ += __shfl_xor(s_, 4, 64); s_ += __shfl_xor(s_, 8, 64);              \
        float e_ = s_ + (eo);                                                  \
        e_ = (e_ >= 0.f) ? e_ : 0.01f * e_;                                    \
        const float m2_ = fmaxf(M, e_);                                        \
        const float c_  = __expf(M - m2_);                                     \
        const float p_  = __expf(e_ - m2_);                                    \
        L = fmaf(L, c_, p_);                                                   \
        v = v * c_ + (z4) * p_;                                                \
        u = u * c_ + (x4) * p_;                                                \
        M = m2_;                                                               \
    } while (0)

    // ---- single streaming pass: 8 rows per iteration (2 per group) ----
    for (int i = 0; i < cnt_p; i += 8) {
        const int na = ln_s[wv][i + g];
        const int nb = ln_s[wv][i + 4 + g];
        const float ea = le_s[wv][i + g];
        const float eb = le_s[wv][i + 4 + g];
        const v4f za = __builtin_nontemporal_load(
            (const v4f*)(zP + (size_t)na * ZROW) + q);
        const v4f zb4 = __builtin_nontemporal_load(
            (const v4f*)(zP + (size_t)nb * ZROW) + q);
        const v4f xa  = *((const v4f*)(xP + ((size_t)na << 6)) + q);
        const v4f xb4 = *((const v4f*)(xP + ((size_t)nb << 6)) + q);
        UPD(za, xa, ea);
        UPD(zb4, xb4, eb);
    }
    #undef UPD

    // ---- merge the 4 groups within the wave (xor folds over 16/32) ----
    float Mw = M;
    Mw = fmaxf(Mw, __shfl_xor(Mw, 16, 64));
    Mw = fmaxf(Mw, __shfl_xor(Mw, 32, 64));
    const float cg = __expf(M - Mw);               // per-group rescale
    float Lw = L * cg;
    Lw += __shfl_xor(Lw, 16, 64);
    Lw += __shfl_xor(Lw, 32, 64);
    v *= cg;
    u *= cg;
    v.x += __shfl_xor(v.x, 16, 64); v.y += __shfl_xor(v.y, 16, 64);
    v.z += __shfl_xor(v.z, 16, 64); v.w += __shfl_xor(v.w, 16, 64);
    v.x += __shfl_xor(v.x, 32, 64); v.y += __shfl_xor(v.y, 32, 64);
    v.z += __shfl_xor(v.z, 32, 64); v.w += __shfl_xor(v.w, 32, 64);
    u.x += __shfl_xor(u.x, 16, 64); u.y += __shfl_xor(u.y, 16, 64);
    u.z += __shfl_xor(u.z, 16, 64); u.w += __shfl_xor(u.w, 16, 64);
    u.x += __shfl_xor(u.x, 32, 64); u.y += __shfl_xor(u.y, 32, 64);
    u.z += __shfl_xor(u.z, 32, 64); u.w += __shfl_xor(u.w, 32, 64);

    if (ln < 16) {
        ((v4f*)vws[wv])[q] = v;
        ((v4f*)uws[wv])[q] = u;
    }
    if (ln == 0) { mred[wv] = Mw; lred[wv] = Lw; }
    __syncthreads();

    // ---- cross-wave online-softmax merge ----
    if (tid < 64) {
        const float Mg = fmaxf(fmaxf(mred[0], mred[1]), fmaxf(mred[2], mred[3]));
        const float c0 = __expf(mred[0] - Mg);
        const float c1 = __expf(mred[1] - Mg);
        const float c2 = __expf(mred[2] - Mg);
        const float c3 = __expf(mred[3] - Mg);
        const float Lg = c0 * lred[0] + c1 * lred[1] + c2 * lred[2] + c3 * lred[3];
        const float inv = (Lg > 0.f) ? (1.f / Lg) : 0.f;   // row_empty -> 0
        vs_s[tid] = (c0 * vws[0][tid] + c1 * vws[1][tid] +
                     c2 * vws[2][tid] + c3 * vws[3][tid]) * inv;
        us_s[tid] = (c0 * uws[0][tid] + c1 * uws[1][tid] +
                     c2 * uws[2][tid] + c3 * uws[3][tid]) * inv;
        ys_s[tid] = y[(size_t)bm * 64 + tid];
    }
    __syncthreads();

    // ---- fused epilogue: h = v@We + u@Wop + y@Wma ; waves split i ----
    {
        float acc = 0.f;
        const int i0 = wv * 16;
        #pragma unroll
        for (int k = 0; k < 16; ++k) {
            const int i = i0 + k;
            acc += vs_s[i] * Wedge[i * 64 + ln]
                 + us_s[i] * Wop[i * 64 + ln]
                 + ys_s[i] * Wma[i * 64 + ln];
        }
        pvt[wv][ln] = acc;
    }
    __syncthreads();
    if (tid < 64) {
        const float h = pvt[0][tid] + pvt[1][tid] + pvt[2][tid] + pvt[3][tid];
        out[(size_t)bm * 64 + tid] = (h > 0.f) ? h : (__expf(h) - 1.f);
    }
}

extern "C" void kernel_launch(void* const* d_in, const int* in_sizes, int n_in,
                              void* d_out, int out_size, void* d_ws, size_t ws_size,
                              hipStream_t stream) {
    const float* x     = (const float*)d_in[0];
    const float* y     = (const float*)d_in[1];
    const float* z     = (const float*)d_in[2];
    const int*   adj   = (const int*)d_in[3];
    const float* Wop   = (const float*)d_in[4];
    const float* Wma   = (const float*)d_in[5];
    const float* Wedge = (const float*)d_in[6];
    const float* att   = (const float*)d_in[7];

    float* ws     = (float*)d_ws;
    float* ws_we  = ws;                              // 64
    float* ws_eop = ws + 64;                         // B*OP = 3200
    float* ws_ema = ws + 64 + B_ * OP_;              // B*MA = 1600

    precompute_k<<<1200, 256, 0, stream>>>(
        x, y, Wop, Wma, Wedge, att, ws_we, ws_eop, ws_ema);
    gat_fused<<<B_ * MA_, 256, 0, stream>>>(
        x, y, z, adj, Wop, Wma, Wedge, ws_we, ws_eop, ws_ema, (float*)d_out);
}

// Round 7
// 234.951 us; speedup vs baseline: 1.0650x; 1.0219x over previous
//
#include <hip/hip_runtime.h>
#include <math.h>

// EdgeGAT: B=8, OP=400, MA=200, F=64. f32 in/out, adj int32.
// v4 (resubmit — broker timeout, never measured): v3.1 + latency/ILP levers:
//  - depth-1 register prefetch (lists padded +8 sentinels -> branch-free)
//  - dual independent online-softmax states per group (breaks serial chain)
//  - single-exp update (exp(min-max) selected into c/p)
//  - (n,e) packed as int2 in LDS -> ds_read_b64, 2 reads/iter
// Block = (b,m), 4 waves x 100 rows, quad-of-16 layout:
//   lane = (group g=ln>>4 owns a row, quad q=ln&15 owns 4 features)
//   1 dwordx4 load = 4 z-rows; dot = 4 intra-16 shfl_xor shared by 4 rows.
#define B_   8
#define OP_  400
#define MA_  200
#define ZROW (MA_ * 64)
#define NEGM -1.0e30f

typedef float v4f __attribute__((ext_vector_type(4)));

// ---------------- kernel 1: precompute (wave-per-row) ----------------
__global__ __launch_bounds__(256) void precompute_k(
    const float* __restrict__ x, const float* __restrict__ y,
    const float* __restrict__ Wop, const float* __restrict__ Wma,
    const float* __restrict__ Wedge, const float* __restrict__ att,
    float* __restrict__ ws_we, float* __restrict__ ws_eop, float* __restrict__ ws_ema)
{
    __shared__ float w_s[192];
    const int tid = threadIdx.x, wv = tid >> 6, ln = tid & 63;
    if (tid < 192) {
        const int which = tid >> 6, i = tid & 63;
        const float* W = (which == 0) ? Wop : ((which == 1) ? Wma : Wedge);
        const float* a = att + which * 64;
        float acc = 0.f;
        #pragma unroll 8
        for (int f = 0; f < 64; ++f) acc = fmaf(W[i * 64 + f], a[f], acc);
        w_s[tid] = acc;
    }
    __syncthreads();
    if (blockIdx.x == 0 && tid < 64) ws_we[tid] = w_s[128 + tid];

    const int row = blockIdx.x * 4 + wv;           // 0 .. 4799
    if (row < B_ * OP_) {
        float s = x[(size_t)row * 64 + ln] * w_s[ln];
        #pragma unroll
        for (int o = 32; o > 0; o >>= 1) s += __shfl_xor(s, o, 64);
        if (ln == 0) ws_eop[row] = s;
    } else if (row < B_ * OP_ + B_ * MA_) {
        const int r2 = row - B_ * OP_;
        float s = y[(size_t)r2 * 64 + ln] * w_s[64 + ln];
        #pragma unroll
        for (int o = 32; o > 0; o >>= 1) s += __shfl_xor(s, o, 64);
        if (ln == 0) ws_ema[r2] = s;
    }
}

// ---------------- kernel 2: fused stream + softmax + epilogue ----------------
__global__ __launch_bounds__(256) void gat_fused(
    const float* __restrict__ x, const float* __restrict__ y,
    const float* __restrict__ z, const int* __restrict__ adj,
    const float* __restrict__ Wop, const float* __restrict__ Wma,
    const float* __restrict__ Wedge,
    const float* __restrict__ ws_we, const float* __restrict__ ws_eop,
    const float* __restrict__ ws_ema, float* __restrict__ out)
{
    __shared__ int2  nle[4][112];      // packed (n, e) per wave; pad sentinels
    __shared__ float mred[4], lred[4];
    __shared__ float vws[4][64], uws[4][64];
    __shared__ float vs_s[64], us_s[64], ys_s[64];
    __shared__ float pvt[4][64];

    const int tid = threadIdx.x, wv = tid >> 6, ln = tid & 63;
    const int g = ln >> 4, q = ln & 15;            // group / feature-quad
    const int bm = blockIdx.x;
    const int b = bm / MA_, m = bm % MA_;

    const float ema = ws_ema[bm];

    // ---- per-wave active-row compaction (rows rbase..rbase+99) ----
    const int rbase = wv * 100;
    int cnt = 0;
    #pragma unroll
    for (int round = 0; round < 2; ++round) {
        const int lr = round * 64 + ln;            // 0..127
        const int n  = rbase + lr;
        bool a = false;
        if (lr < 100) a = (adj[((size_t)(b * OP_ + n)) * MA_ + m] != 0);
        const unsigned long long mask = __ballot(a);
        if (a) {
            const int pos = cnt + __popcll(mask & ((1ull << ln) - 1ull));
            nle[wv][pos] = make_int2(n, __float_as_int(ws_eop[b * OP_ + n] + ema));
        }
        cnt += __popcll(mask);
    }
    // pad through cnt_p+8 with sentinels so depth-1 prefetch is branch-free
    const int cnt_p = (cnt + 7) & ~7;              // <= 104
    if (ln < cnt_p + 8 - cnt) {                    // 8..15 lanes write
        nle[wv][cnt + ln] = make_int2(rbase, __float_as_int(NEGM));
    }
    // list is per-wave (no cross-wave reads): no barrier needed here.

    const float* zP = z + ((size_t)b * OP_ * MA_ + m) * 64;
    const float* xP = x + (size_t)b * OP_ * 64;
    const v4f wq = ((const v4f*)ws_we)[q];         // w_e quad for this lane

    // dual independent states (a-rows / b-rows) per group
    v4f v0 = {0.f,0.f,0.f,0.f}, u0 = {0.f,0.f,0.f,0.f};
    v4f v1 = {0.f,0.f,0.f,0.f}, u1 = {0.f,0.f,0.f,0.f};
    float M0 = NEGM, L0 = 0.f, M1 = NEGM, L1 = 0.f;

    // single-exp online-softmax update; 4 intra-16 shuffles shared by quad
    auto upd = [&wq](float& M, float& L, v4f& v, v4f& u,
                     const v4f z4, const v4f x4, const float eo) {
        float s_ = fmaf(z4.x, wq.x, fmaf(z4.y, wq.y,
                   fmaf(z4.z, wq.z, z4.w * wq.w)));
        s_ += __shfl_xor(s_, 1, 64); s_ += __shfl_xor(s_, 2, 64);
        s_ += __shfl_xor(s_, 4, 64); s_ += __shfl_xor(s_, 8, 64);
        float e_ = s_ + eo;
        e_ = (e_ >= 0.f) ? e_ : 0.01f * e_;
        const float m2_ = fmaxf(M, e_);
        const float w_  = __expf(fminf(M, e_) - m2_);   // one exp
        const bool  nm  = (e_ > M);
        const float c_  = nm ? w_ : 1.f;
        const float p_  = nm ? 1.f : w_;
        L = fmaf(L, c_, p_);
        v = v * c_ + z4 * p_;
        u = u * c_ + x4 * p_;
        M = m2_;
    };

    // ---- streaming pass: 8 rows/iter, depth-1 prefetch ----
    int2 pa = nle[wv][g];
    int2 pb = nle[wv][4 + g];
    v4f za = __builtin_nontemporal_load((const v4f*)(zP + (size_t)pa.x * ZROW) + q);
    v4f zb = __builtin_nontemporal_load((const v4f*)(zP + (size_t)pb.x * ZROW) + q);
    v4f xa = *((const v4f*)(xP + ((size_t)pa.x << 6)) + q);
    v4f xb = *((const v4f*)(xP + ((size_t)pb.x << 6)) + q);

    for (int i = 0; i < cnt_p; i += 8) {
        const int2 qa = nle[wv][i + 8 + g];        // prefetch next (sentinel-safe)
        const int2 qb = nle[wv][i + 12 + g];
        const v4f nza = __builtin_nontemporal_load((const v4f*)(zP + (size_t)qa.x * ZROW) + q);
        const v4f nzb = __builtin_nontemporal_load((const v4f*)(zP + (size_t)qb.x * ZROW) + q);
        const v4f nxa = *((const v4f*)(xP + ((size_t)qa.x << 6)) + q);
        const v4f nxb = *((const v4f*)(xP + ((size_t)qb.x << 6)) + q);
        upd(M0, L0, v0, u0, za, xa, __int_as_float(pa.y));
        upd(M1, L1, v1, u1, zb, xb, __int_as_float(pb.y));
        pa = qa; pb = qb; za = nza; zb = nzb; xa = nxa; xb = nxb;
    }

    // ---- merge dual states ----
    const float Mp = fmaxf(M0, M1);
    const float ca = __expf(M0 - Mp), cb = __expf(M1 - Mp);
    float L = L0 * ca + L1 * cb;
    v4f  v = v0 * ca + v1 * cb;
    v4f  u = u0 * ca + u1 * cb;
    float M = Mp;

    // ---- merge the 4 groups within the wave (xor folds over 16/32) ----
    float Mw = M;
    Mw = fmaxf(Mw, __shfl_xor(Mw, 16, 64));
    Mw = fmaxf(Mw, __shfl_xor(Mw, 32, 64));
    const float cg = __expf(M - Mw);               // per-group rescale
    float Lw = L * cg;
    Lw += __shfl_xor(Lw, 16, 64);
    Lw += __shfl_xor(Lw, 32, 64);
    v *= cg;
    u *= cg;
    v.x += __shfl_xor(v.x, 16, 64); v.y += __shfl_xor(v.y, 16, 64);
    v.z += __shfl_xor(v.z, 16, 64); v.w += __shfl_xor(v.w, 16, 64);
    v.x += __shfl_xor(v.x, 32, 64); v.y += __shfl_xor(v.y, 32, 64);
    v.z += __shfl_xor(v.z, 32, 64); v.w += __shfl_xor(v.w, 32, 64);
    u.x += __shfl_xor(u.x, 16, 64); u.y += __shfl_xor(u.y, 16, 64);
    u.z += __shfl_xor(u.z, 16, 64); u.w += __shfl_xor(u.w, 16, 64);
    u.x += __shfl_xor(u.x, 32, 64); u.y += __shfl_xor(u.y, 32, 64);
    u.z += __shfl_xor(u.z, 32, 64); u.w += __shfl_xor(u.w, 32, 64);

    if (ln < 16) {
        ((v4f*)vws[wv])[q] = v;
        ((v4f*)uws[wv])[q] = u;
    }
    if (ln == 0) { mred[wv] = Mw; lred[wv] = Lw; }
    __syncthreads();

    // ---- cross-wave online-softmax merge ----
    if (tid < 64) {
        const float Mg = fmaxf(fmaxf(mred[0], mred[1]), fmaxf(mred[2], mred[3]));
        const float c0 = __expf(mred[0] - Mg);
        const float c1 = __expf(mred[1] - Mg);
        const float c2 = __expf(mred[2] - Mg);
        const float c3 = __expf(mred[3] - Mg);
        const float Lg = c0 * lred[0] + c1 * lred[1] + c2 * lred[2] + c3 * lred[3];
        const float inv = (Lg > 0.f) ? (1.f / Lg) : 0.f;   // row_empty -> 0
        vs_s[tid] = (c0 * vws[0][tid] + c1 * vws[1][tid] +
                     c2 * vws[2][tid] + c3 * vws[3][tid]) * inv;
        us_s[tid] = (c0 * uws[0][tid] + c1 * uws[1][tid] +
                     c2 * uws[2][tid] + c3 * uws[3][tid]) * inv;
        ys_s[tid] = y[(size_t)bm * 64 + tid];
    }
    __syncthreads();

    // ---- fused epilogue: h = v@We + u@Wop + y@Wma ; waves split i ----
    {
        float acc = 0.f;
        const int i0 = wv * 16;
        #pragma unroll
        for (int k = 0; k < 16; ++k) {
            const int i = i0 + k;
            acc += vs_s[i] * Wedge[i * 64 + ln]
                 + us_s[i] * Wop[i * 64 + ln]
                 + ys_s[i] * Wma[i * 64 + ln];
        }
        pvt[wv][ln] = acc;
    }
    __syncthreads();
    if (tid < 64) {
        const float h = pvt[0][tid] + pvt[1][tid] + pvt[2][tid] + pvt[3][tid];
        out[(size_t)bm * 64 + tid] = (h > 0.f) ? h : (__expf(h) - 1.f);
    }
}

extern "C" void kernel_launch(void* const* d_in, const int* in_sizes, int n_in,
                              void* d_out, int out_size, void* d_ws, size_t ws_size,
                              hipStream_t stream) {
    const float* x     = (const float*)d_in[0];
    const float* y     = (const float*)d_in[1];
    const float* z     = (const float*)d_in[2];
    const int*   adj   = (const int*)d_in[3];
    const float* Wop   = (const float*)d_in[4];
    const float* Wma   = (const float*)d_in[5];
    const float* Wedge = (const float*)d_in[6];
    const float* att   = (const float*)d_in[7];

    float* ws     = (float*)d_ws;
    float* ws_we  = ws;                              // 64
    float* ws_eop = ws + 64;                         // B*OP = 3200
    float* ws_ema = ws + 64 + B_ * OP_;              // B*MA = 1600

    precompute_k<<<1200, 256, 0, stream>>>(
        x, y, Wop, Wma, Wedge, att, ws_we, ws_eop, ws_ema);
    gat_fused<<<B_ * MA_, 256, 0, stream>>>(
        x, y, z, adj, Wop, Wma, Wedge, ws_we, ws_eop, ws_ema, (float*)d_out);
}